// Round 2
// baseline (209.387 us; speedup 1.0000x reference)
//
#include <hip/hip_runtime.h>
#include <math.h>

namespace {

constexpr int RAD  = 6;
constexpr int P    = 13;
constexpr int NWIN = 169;   // P*P
constexpr int NTOT = 338;   // 2 refs * NWIN
constexpr int NCH  = 128;
constexpr int NCLS = 32;
constexpr int W    = 64;
constexpr int HW   = 4096;
constexpr float FOUR_LN2 = 2.772588722239781f;

typedef float f4u __attribute__((ext_vector_type(4), aligned(4)));

__device__ __forceinline__ bool better(float va, int ia, float vb, int ib) {
  return (va > vb) || ((va == vb) && (ia < ib));
}

__global__ __launch_bounds__(384) void colorizer_kernel(
    const float* __restrict__ fr,   // [2][2][128][64][64]  (nref,b,c,y,x)
    const float* __restrict__ ft,   // [2][128][64][64]
    const int*  __restrict__ q,     // [2][2][1][256][256]
    float* __restrict__ out) {      // [2][32][64][64]
  const int blk = blockIdx.x;           // b*1024 + y*16 + xs
  const int b     = blk >> 10;
  const int y     = (blk >> 4) & 63;
  const int xbase = (blk & 15) << 2;    // strip of 4 pixels along x
  const int t = threadIdx.x;
  const int wid  = t >> 6;
  const int lane = t & 63;

  __shared__ float4 T4[NCH];            // target vecs for the 4 pixels
  __shared__ float  s[4][NTOT];         // probs per pixel
  __shared__ float4 wredA[6], wredB[6];
  __shared__ float  accS[4][NCLS];
  __shared__ float  params[2][4][8];    // per (ref,pixel): flag,w0,xs0,ys0,w1,xs1,ys1

  if (t < NCH) {
    const float* tp = ft + (size_t)(b * NCH + t) * HW + y * W + xbase;
    T4[t] = *(const float4*)tp;         // 16B aligned (xbase % 4 == 0)
  }
  if (t < 4 * NCLS) ((float*)accS)[t] = 0.f;
  __syncthreads();

  const bool act = (t < NTOT);
  const int i   = (t >= NWIN) ? 1 : 0;
  const int m   = t - i * NWIN;
  const int dy  = m / P;
  const int dx  = m - dy * P;
  const int yy  = y + dy - RAD;
  const int xx0 = xbase + dx - RAD;     // leftmost pixel's window column
  const bool yy_ok = ((unsigned)yy < 64u);

  // ---------- phase 1: correlation dots for 4 pixels ----------
  float4 acc = make_float4(0.f, 0.f, 0.f, 0.f);
  if (act && yy_ok) {
    const float* rp = fr + (size_t)((i * 2 + b) * NCH) * HW + yy * W;
    if (xx0 >= 0 && xx0 <= 60) {
      const float* p0 = rp + xx0;
      #pragma unroll 8
      for (int c = 0; c < NCH; ++c) {
        const f4u rv = *(const f4u*)(p0 + (size_t)c * HW);
        const float4 tv = T4[c];
        acc.x = fmaf(tv.x, rv.x, acc.x);
        acc.y = fmaf(tv.y, rv.y, acc.y);
        acc.z = fmaf(tv.z, rv.z, acc.z);
        acc.w = fmaf(tv.w, rv.w, acc.w);
      }
    } else {
      // boundary strip: masked scalar loads
      const unsigned ux0 = (unsigned)xx0, ux1 = (unsigned)(xx0 + 1),
                     ux2 = (unsigned)(xx0 + 2), ux3 = (unsigned)(xx0 + 3);
      const float m0 = (ux0 < 64u) ? 1.f : 0.f, m1 = (ux1 < 64u) ? 1.f : 0.f,
                  m2 = (ux2 < 64u) ? 1.f : 0.f, m3 = (ux3 < 64u) ? 1.f : 0.f;
      const int o0 = (ux0 < 64u) ? (int)ux0 : 0, o1 = (ux1 < 64u) ? (int)ux1 : 0,
                o2 = (ux2 < 64u) ? (int)ux2 : 0, o3 = (ux3 < 64u) ? (int)ux3 : 0;
      #pragma unroll 4
      for (int c = 0; c < NCH; ++c) {
        const float* rc = rp + (size_t)c * HW;
        const float4 tv = T4[c];
        acc.x = fmaf(tv.x, rc[o0] * m0, acc.x);
        acc.y = fmaf(tv.y, rc[o1] * m1, acc.y);
        acc.z = fmaf(tv.z, rc[o2] * m2, acc.z);
        acc.w = fmaf(tv.w, rc[o3] * m3, acc.w);
      }
    }
  }

  // ---------- phase 2: joint softmax over 338 (per pixel, componentwise) ----------
  float4 v;
  v.x = act ? acc.x : -INFINITY;
  v.y = act ? acc.y : -INFINITY;
  v.z = act ? acc.z : -INFINITY;
  v.w = act ? acc.w : -INFINITY;
  {
    float4 r = v;
    for (int off = 32; off > 0; off >>= 1) {
      r.x = fmaxf(r.x, __shfl_xor(r.x, off));
      r.y = fmaxf(r.y, __shfl_xor(r.y, off));
      r.z = fmaxf(r.z, __shfl_xor(r.z, off));
      r.w = fmaxf(r.w, __shfl_xor(r.w, off));
    }
    if (lane == 0) wredA[wid] = r;
  }
  __syncthreads();
  float4 g = wredA[0];
  #pragma unroll
  for (int k = 1; k < 6; ++k) {
    g.x = fmaxf(g.x, wredA[k].x); g.y = fmaxf(g.y, wredA[k].y);
    g.z = fmaxf(g.z, wredA[k].z); g.w = fmaxf(g.w, wredA[k].w);
  }
  float4 e;
  e.x = act ? __expf(v.x - g.x) : 0.f;
  e.y = act ? __expf(v.y - g.y) : 0.f;
  e.z = act ? __expf(v.z - g.z) : 0.f;
  e.w = act ? __expf(v.w - g.w) : 0.f;
  {
    float4 r = e;
    for (int off = 32; off > 0; off >>= 1) {
      r.x += __shfl_xor(r.x, off);
      r.y += __shfl_xor(r.y, off);
      r.z += __shfl_xor(r.z, off);
      r.w += __shfl_xor(r.w, off);
    }
    if (lane == 0) wredB[wid] = r;
  }
  __syncthreads();
  float4 gs = wredB[0];
  #pragma unroll
  for (int k = 1; k < 6; ++k) {
    gs.x += wredB[k].x; gs.y += wredB[k].y; gs.z += wredB[k].z; gs.w += wredB[k].w;
  }
  float pr0 = e.x / gs.x, pr1 = e.y / gs.y, pr2 = e.z / gs.z, pr3 = e.w / gs.w;
  if (act) { s[0][t] = pr0; s[1][t] = pr1; s[2][t] = pr2; s[3][t] = pr3; }
  __syncthreads();

  // ---------- phase 3: top-2 per (ref,pixel) — 8 tasks on 32-lane groups ----------
  if (wid < 4) {
    const int tt = (wid << 1) | (lane >> 5);   // 0..7
    const int ii = tt >> 2;
    const int jj = tt & 3;
    const int l32 = lane & 31;
    float v1 = -1.f, v2 = -1.f;
    int i1 = 1 << 20, i2 = 1 << 20;
    for (int mm = l32; mm < NWIN; mm += 32) {
      const float pv = s[jj][ii * NWIN + mm];
      if (better(pv, mm, v1, i1)) { v2 = v1; i2 = i1; v1 = pv; i1 = mm; }
      else if (better(pv, mm, v2, i2)) { v2 = pv; i2 = mm; }
    }
    for (int off = 16; off > 0; off >>= 1) {
      const float u1 = __shfl_xor(v1, off); const int j1 = __shfl_xor(i1, off);
      const float u2 = __shfl_xor(v2, off); const int j2 = __shfl_xor(i2, off);
      if (better(u1, j1, v1, i1)) {
        float nv2; int ni2;
        if (better(v1, i1, u2, j2)) { nv2 = v1; ni2 = i1; }
        else                        { nv2 = u2; ni2 = j2; }
        v1 = u1; i1 = j1; v2 = nv2; i2 = ni2;
      } else if (better(u1, j1, v2, i2)) {
        v2 = u1; i2 = j1;
      }
    }
    if (l32 == 0) {
      const float e1 = __expf(v1);
      const float e2 = __expf(v2);
      const float rs = 1.f / (e1 + e2);
      float* pp = params[ii][jj];
      pp[0] = (v1 > 0.1f) ? 1.f : 0.f;
      pp[1] = e1 * rs;
      pp[2] = (float)(i1 % P);
      pp[3] = (float)(i1 / P);
      pp[4] = e2 * rs;
      pp[5] = (float)(i2 % P);
      pp[6] = (float)(i2 / P);
    }
  }
  __syncthreads();

  // ---------- phase 4: corr2 + label scatter ----------
  if (act) {
    const int qbase = (i * 2 + b) * 65536 + (yy * 4) * 256;
    const float pr[4] = {pr0, pr1, pr2, pr3};
    #pragma unroll
    for (int j = 0; j < 4; ++j) {
      const float* pp = params[i][j];
      float val;
      if (pp[0] != 0.f) {
        const float fdx0 = (float)dx - pp[2];
        const float fdy0 = (float)dy - pp[3];
        const float fdx1 = (float)dx - pp[5];
        const float fdy1 = (float)dy - pp[6];
        val = pp[1] * __expf(-FOUR_LN2 * (fdx0 * fdx0 + fdy0 * fdy0))
            + pp[4] * __expf(-FOUR_LN2 * (fdx1 * fdx1 + fdy1 * fdy1));
      } else {
        val = pr[j];
      }
      const int xj = xx0 + j;
      if (yy_ok && (unsigned)xj < 64u) {
        const int cls = q[qbase + xj * 4];
        atomicAdd(&accS[j][cls], val);
      }
    }
  }
  __syncthreads();

  // ---------- phase 5: write output ----------
  if (t < 4 * NCLS) {
    const int cls = t >> 2;
    const int j   = t & 3;
    const float sc = (cls == 0) ? 1.0f : 1.15f;
    out[(size_t)(b * NCLS + cls) * HW + y * W + xbase + j] = accS[j][cls] * sc;
  }
}

}  // namespace

extern "C" void kernel_launch(void* const* d_in, const int* in_sizes, int n_in,
                              void* d_out, int out_size, void* d_ws, size_t ws_size,
                              hipStream_t stream) {
  const float* fr = (const float*)d_in[0];   // feats_r
  const float* ft = (const float*)d_in[1];   // feats_t
  const int*   q  = (const int*)d_in[2];     // quantized_r
  float* out = (float*)d_out;
  colorizer_kernel<<<dim3(2 * HW / 4), dim3(384), 0, stream>>>(fr, ft, q, out);
}